// Round 11
// baseline (498.349 us; speedup 1.0000x reference)
//
#include <hip/hip_runtime.h>
#include <hip/hip_bf16.h>
#include <math.h>

typedef __bf16 bf16_t;
typedef __bf16 bf16x8 __attribute__((ext_vector_type(8)));
typedef __bf16 bf16x4 __attribute__((ext_vector_type(4)));
typedef float floatx4 __attribute__((ext_vector_type(4)));

#define BATCH 65536L
#define ROWS 64
#define MFMA __builtin_amdgcn_mfma_f32_16x16x32_bf16

// ---------------- helpers ----------------

__device__ __forceinline__ float softplus_f(float x) {
  const float l = __logf(1.f + __expf(x));
  return (x > 15.f) ? x : l;
}
__device__ __forceinline__ float sigmoid_f(float x) {
  return __builtin_amdgcn_rcpf(1.f + __expf(-x));
}

// fragment-linear activation store/load: element block (row=mf*16+lr, cols c0..c0+3)
__device__ __forceinline__ void store_frag(char* buf, int NKT, int mf, int c0, int lr, bf16x4 v) {
  const int kt = c0 >> 5, lkp = (c0 & 31) >> 3, j0 = c0 & 7;
  *(bf16x4*)(buf + (((mf * NKT + kt) * 64) + lr + 16 * lkp) * 16 + j0 * 2) = v;
}
__device__ __forceinline__ bf16x4 load_frag(const char* buf, int NKT, int mf, int c0, int lr) {
  const int kt = c0 >> 5, lkp = (c0 & 31) >> 3, j0 = c0 & 7;
  return *(const bf16x4*)(buf + (((mf * NKT + kt) * 64) + lr + 16 * lkp) * 16 + j0 * 2);
}

// ---------------- ping-pong frag-linear GEMM (R17-verified loop, any MF/NF) ------
// Weights kt-major: [kt][NT][lane][8]. A from LDS: [mf][KT][lane][8].
// R28: TRANSPOSED WAVE GRID for G1/G2/G3 -- 2 row-groups x 4 col-groups
// (MF=2, NF=4, 2 passes) instead of 1x8 (MF=4, NF=2, 2 passes).
//   * A-traffic per wave HALVES (64 KB vs 128 KB per 512-col GEMM): LDS reads
//     were the largest per-CU floor (~197us of the 445us wall).
//   * Register shape is IDENTICAL to the proven R17 geometry (operands 48 +
//     acc 32; 8-MFMA cluster per 6 covered loads) -> no 128-reg-wall risk.
//   * Each weight tile is read by the 2 waves of a row-group pair -- same CU,
//     barrier-lockstep -> per-CU L1 dedups the second stream (unlike R24's
//     cross-CU split which doubled L2 and lost 23%).
// G4 + z-update keep the 1x8 decomposition (in-register, unchanged).

template<int MF, int KT, int NT, int NF>
__device__ __forceinline__ void gemmP(const char* Abuf, const bf16_t* W, int ntb,
                                      int lane, floatx4 (&acc)[MF][NF])
{
  const char* wp = (const char*)W + (ntb * 64 + lane) * 16;
  const char* ap = Abuf + lane * 16;
  bf16x8 bv0[NF], bv1[NF];
  bf16x8 aA[MF], aB[MF];
#pragma unroll
  for (int nf = 0; nf < NF; ++nf) bv0[nf] = *(const bf16x8*)(wp + nf * 1024);
#pragma unroll
  for (int m = 0; m < MF; ++m) aA[m] = *(const bf16x8*)(ap + m * KT * 1024);
#pragma unroll 1
  for (int kt = 0; kt < KT; kt += 2) {
#pragma unroll
    for (int nf = 0; nf < NF; ++nf)
      bv1[nf] = *(const bf16x8*)(wp + NT * 1024 + nf * 1024);
#pragma unroll
    for (int m = 0; m < MF; ++m)
      aB[m] = *(const bf16x8*)(ap + 1024 + m * KT * 1024);
    __builtin_amdgcn_s_setprio(1);
#pragma unroll
    for (int m = 0; m < MF; ++m)
#pragma unroll
      for (int nf = 0; nf < NF; ++nf)
        acc[m][nf] = MFMA(bv0[nf], aA[m], acc[m][nf], 0, 0, 0);
    __builtin_amdgcn_s_setprio(0);
    if (kt + 2 < KT) {
#pragma unroll
      for (int nf = 0; nf < NF; ++nf)
        bv0[nf] = *(const bf16x8*)(wp + 2 * NT * 1024 + nf * 1024);
#pragma unroll
      for (int m = 0; m < MF; ++m)
        aA[m] = *(const bf16x8*)(ap + 2048 + m * KT * 1024);
    }
    __builtin_amdgcn_s_setprio(1);
#pragma unroll
    for (int m = 0; m < MF; ++m)
#pragma unroll
      for (int nf = 0; nf < NF; ++nf)
        acc[m][nf] = MFMA(bv1[nf], aB[m], acc[m][nf], 0, 0, 0);
    __builtin_amdgcn_s_setprio(0);
    wp += 2 * NT * 1024;
    ap += 2048;
  }
}

// GEMM1: K=192 = zf_dyn (NKT=4) + zstat (NKT=2); weights NT=32, KT=6; kt pairs
// (0,1),(2,3) read zf; (4,5) read zst. MF=2, NF=4 (transposed grid); zf/zs
// pointers arrive pre-offset by the wave's row-group.
__device__ __forceinline__ void gemm_g1(const char* zf, const char* zs, const bf16_t* W,
                                        int ntb, int lane, floatx4 (&acc)[2][4])
{
  const char* wp = (const char*)W + (ntb * 64 + lane) * 16;
  bf16x8 bv0[4], bv1[4];
#pragma unroll
  for (int nf = 0; nf < 4; ++nf) bv0[nf] = *(const bf16x8*)(wp + nf * 1024);
#pragma unroll 1
  for (int kt = 0; kt < 6; kt += 2) {
    const char* ab = (kt < 4) ? (zf + kt * 1024 + lane * 16)
                              : (zs + (kt - 4) * 1024 + lane * 16);
    const int  ms = (kt < 4) ? 4096 : 2048;   // mf stride (NKT*1024)
#pragma unroll
    for (int nf = 0; nf < 4; ++nf)
      bv1[nf] = *(const bf16x8*)(wp + 32 * 1024 + nf * 1024);
    bf16x8 a[2];
#pragma unroll
    for (int m = 0; m < 2; ++m) a[m] = *(const bf16x8*)(ab + m * ms);
    __builtin_amdgcn_s_setprio(1);
#pragma unroll
    for (int m = 0; m < 2; ++m)
#pragma unroll
      for (int nf = 0; nf < 4; ++nf)
        acc[m][nf] = MFMA(bv0[nf], a[m], acc[m][nf], 0, 0, 0);
    __builtin_amdgcn_s_setprio(0);
    if (kt + 2 < 6) {
#pragma unroll
      for (int nf = 0; nf < 4; ++nf)
        bv0[nf] = *(const bf16x8*)(wp + 64 * 1024 + nf * 1024);
    }
#pragma unroll
    for (int m = 0; m < 2; ++m) a[m] = *(const bf16x8*)(ab + 1024 + m * ms);
    __builtin_amdgcn_s_setprio(1);
#pragma unroll
    for (int m = 0; m < 2; ++m)
#pragma unroll
      for (int nf = 0; nf < 4; ++nf)
        acc[m][nf] = MFMA(bv1[nf], a[m], acc[m][nf], 0, 0, 0);
    __builtin_amdgcn_s_setprio(0);
    wp += 64 * 1024;
  }
}

// ---------------- fused kernel: 64 rows/block, 8 waves (512 thr), 1 block/CU ------

__global__ __launch_bounds__(512, 1)
void ham_fused(const float* __restrict__ z_dyn, const float* __restrict__ z_static,
               const float* __restrict__ dtp, const float* __restrict__ ut,
               const float* __restrict__ b1, const float* __restrict__ b2,
               const bf16_t* __restrict__ W1s, const bf16_t* __restrict__ W2s,
               const bf16_t* __restrict__ W2ts, const bf16_t* __restrict__ W1ts,
               const float* __restrict__ Bc, const float* __restrict__ Cm,
               const float* __restrict__ Dm,
               float* __restrict__ z_out, float* __restrict__ yt_out)
{
  __shared__ __align__(16) char bufX[65536];   // h1 -> g1 (NKT=16, mf 0..3); later f32 z (stride 132)
  __shared__ __align__(16) char bufY[65536];   // zf (NKT=4) -> g2 (NKT=16); later Cm (stride 132)
  __shared__ __align__(16) char zst[8192];     // z_static frags (NKT=2, mf 0..3); later Dm
  __shared__ __align__(16) float uBs[64 * 68]; // uB, padded stride 68

  const int tid  = threadIdx.x;
  const int lane = tid & 63;
  const int w    = tid >> 6;      // 0..7
  const int lr   = lane & 15;
  const int lk   = lane >> 4;     // 0..3
  const long rb  = (long)blockIdx.x * ROWS;
  const int  rgrp = w & 1;        // row-group (rows rgrp*32..+31 -> mf rgrp*2+{0,1})
  const int  cgrp = w >> 1;       // col-group (cols cgrp*128..+127)

  // dt is wave-uniform: pin to SGPR
  const float dtv = __builtin_bit_cast(float,
      __builtin_amdgcn_readfirstlane(__builtin_bit_cast(int, dtp[0])));
  const float hstep = dtv * 0.25f;
  const int   pcb   = ((w + 4) & 7) * 16;   // partner col base for z layout

  // ---- init: Bc -> bufX (f32), z_static -> zst (frag-linear bf16), zp regs
  for (int e = tid; e < 64 * 16; e += 512) ((float*)bufX)[e] = Bc[e];
  for (int e = tid; e < ROWS * 64; e += 512) {
    const int rr = e >> 6, cc = e & 63;
    const float v = __builtin_nontemporal_load(z_static + (rb + rr) * 64 + cc);
    const int kt = cc >> 5, lkp = (cc & 31) >> 3, j = cc & 7;
    *(bf16_t*)(zst + ((((rr >> 4) * 2 + kt) * 64) + (rr & 15) + 16 * lkp) * 16 + j * 2) = (bf16_t)v;
  }
  floatx4 zp[4];
#pragma unroll
  for (int m = 0; m < 4; ++m)
    zp[m] = __builtin_nontemporal_load(
        (const floatx4*)(z_dyn + (rb + m * 16 + lr) * 128 + pcb + lk * 4));
  __syncthreads();

  // ---- uB -> LDS (reads Bc from bufX; bufX reused after B1)
  for (int e = tid; e < ROWS * 64; e += 512) {
    const int rr = e >> 6, cc = e & 63;
    const float* ur = ut + (rb + rr) * 16;
    const float* bc = (const float*)bufX + cc * 16;
    float s = 0.f;
#pragma unroll
    for (int u = 0; u < 16; ++u) s += ur[u] * bc[u];
    uBs[rr * 68 + cc] = s;
  }

  for (int s = 0; s < 4; ++s) {
    // ---- pack zf (bufY, NKT=4) from z regs (all 4 row-frags, own partner cols)
#pragma unroll
    for (int m = 0; m < 4; ++m) {
      bf16x4 o;
#pragma unroll
      for (int i = 0; i < 4; ++i) o[i] = (bf16_t)zp[m][i];
      store_frag(bufY, 4, m, pcb + lk * 4, lr, o);
    }
    __syncthreads();   // B1: zf+uBs ready; everyone past GEMM4/bufX reads (or Bc reads)

    // ---- GEMM1 -> h1 (bufX), two 64-col passes per wave (transposed grid)
#pragma unroll 1
    for (int p = 0; p < 2; ++p) {
      floatx4 acc[2][4] = {};
      gemm_g1(bufY + rgrp * 8192, zst + rgrp * 4096, W1s,
              cgrp * 8 + p * 4, lane, acc);
#pragma unroll
      for (int m = 0; m < 2; ++m)
#pragma unroll
        for (int nf = 0; nf < 4; ++nf) {
          const int c0 = cgrp * 128 + p * 64 + nf * 16 + lk * 4;
          const floatx4 b4 = *(const floatx4*)(b1 + c0);
          bf16x4 h4;
#pragma unroll
          for (int i = 0; i < 4; ++i) h4[i] = (bf16_t)softplus_f(acc[m][nf][i] + b4[i]);
          store_frag(bufX, 16, rgrp * 2 + m, c0, lr, h4);
        }
    }
    __syncthreads();   // B2: h1 ready

    // ---- GEMM2 -> g2 = sigmoid(a2+b2) (bufY), two passes  [w3 folded into W2ts]
#pragma unroll 1
    for (int p = 0; p < 2; ++p) {
      floatx4 acc[2][4] = {};
      gemmP<2, 16, 32, 4>(bufX + rgrp * 32768, W2s, cgrp * 8 + p * 4, lane, acc);
#pragma unroll
      for (int m = 0; m < 2; ++m)
#pragma unroll
        for (int nf = 0; nf < 4; ++nf) {
          const int c0 = cgrp * 128 + p * 64 + nf * 16 + lk * 4;
          const floatx4 b4 = *(const floatx4*)(b2 + c0);
          bf16x4 g4;
#pragma unroll
          for (int i = 0; i < 4; ++i) g4[i] = (bf16_t)sigmoid_f(acc[m][nf][i] + b4[i]);
          store_frag(bufY, 16, rgrp * 2 + m, c0, lr, g4);
        }
    }
    __syncthreads();   // B3: g2 ready

    // ---- GEMM3 -> g1 = s1 * (g2 @ (w3.W2)) (bufX), two passes
#pragma unroll 1
    for (int p = 0; p < 2; ++p) {
      floatx4 acc[2][4] = {};
      gemmP<2, 16, 32, 4>(bufY + rgrp * 32768, W2ts, cgrp * 8 + p * 4, lane, acc);
#pragma unroll
      for (int m = 0; m < 2; ++m)
#pragma unroll
        for (int nf = 0; nf < 4; ++nf) {
          const int c0 = cgrp * 128 + p * 64 + nf * 16 + lk * 4;
          const bf16x4 h4 = load_frag(bufX, 16, rgrp * 2 + m, c0, lr); // lane-private
          bf16x4 g4;
#pragma unroll
          for (int i = 0; i < 4; ++i) {
            const float s1 = 1.f - __expf(-(float)h4[i]);     // sigmoid(a1) from h1
            g4[i] = (bf16_t)(s1 * acc[m][nf][i]);
          }
          store_frag(bufX, 16, rgrp * 2 + m, c0, lr, g4);
        }
    }
    __syncthreads();   // B4: g1 ready

    // ---- GEMM4: dH col block w*16; z update (1x8 grid, partner layout, in regs)
    {
      floatx4 a4[4][1] = {};
      gemmP<4, 16, 8, 1>(bufX, W1ts, w, lane, a4);
#pragma unroll
      for (int m = 0; m < 4; ++m) {
        if (w < 4) {
          const float* ub = &uBs[(m * 16 + lr) * 68 + w * 16 + lk * 4];
#pragma unroll
          for (int i = 0; i < 4; ++i) zp[m][i] += hstep * (ub[i] - a4[m][0][i]);
        } else {
#pragma unroll
          for (int i = 0; i < 4; ++i) zp[m][i] += hstep * a4[m][0][i];
        }
      }
    }
    // next B1 separates GEMM4 bufX reads from GEMM1 bufX writes
  }

  // ---- final z store (nontemporal) + stage for yt (stride 132 floats)
#pragma unroll
  for (int m = 0; m < 4; ++m)
    __builtin_nontemporal_store(zp[m],
        (floatx4*)(z_out + (rb + m * 16 + lr) * 128 + pcb + lk * 4));
  __syncthreads();   // all GEMM4 bufX reads done
#pragma unroll
  for (int m = 0; m < 4; ++m)
    *(floatx4*)((float*)bufX + (m * 16 + lr) * 132 + pcb + lk * 4) = zp[m];
  for (int e = tid; e < 20 * 128; e += 512) {
    const int o = e >> 7, i = e & 127;
    ((float*)bufY)[o * 132 + i] = Cm[e];
  }
  for (int e = tid; e < 20 * 16; e += 512) ((float*)zst)[e] = Dm[e];
  __syncthreads();

  for (int q = tid; q < ROWS * 20; q += 512) {
    const int rr = q / 20, o = q - rr * 20;
    const float* zr = (const float*)bufX + rr * 132;
    const float* cr = (const float*)bufY + o * 132;
    float sm = 0.f;
#pragma unroll 4
    for (int i = 0; i < 128; ++i) sm += zr[i] * cr[i];
    float su = 0.f;
#pragma unroll
    for (int u = 0; u < 16; ++u)
      su += __builtin_nontemporal_load(ut + (rb + rr) * 16 + u) * ((const float*)zst)[o * 16 + u];
    __builtin_nontemporal_store(sm + dtv * su, yt_out + (rb + rr) * 20 + o);
  }
}

// ---------------- prep: kt-major fragment-linear shuffled weights ----------------
// shuf[((kt*NT + nt)*64 + ln)*8 + j] = Bt[nt*16 + (ln&15)][kt*32 + (ln>>4)*8 + j]

__global__ void prep_shuffle(const float* W1, const float* W2, const float* W3,
                             bf16_t* W1s, bf16_t* W2s, bf16_t* W2ts, bf16_t* W1ts)
{
  const long idx = (long)blockIdx.x * 256 + threadIdx.x;
  const long S1 = 98304, S2 = 262144, S3 = 262144, S4 = 65536;
  if (idx < S1) {                                   // Bt = W1 (512 x 192), NT=32, KT=6
    const long e = idx;
    const int j = (int)(e & 7), ln = (int)((e >> 3) & 63), tile = (int)(e >> 9);
    const int nt = tile & 31, kt = tile >> 5;
    const int srow = nt * 16 + (ln & 15), scol = kt * 32 + (ln >> 4) * 8 + j;
    W1s[e] = (bf16_t)W1[srow * 192 + scol];
  } else if (idx < S1 + S2) {                       // Bt = W2 (512 x 512), NT=32, KT=16
    const long e = idx - S1;
    const int j = (int)(e & 7), ln = (int)((e >> 3) & 63), tile = (int)(e >> 9);
    const int nt = tile & 31, kt = tile >> 5;
    const int srow = nt * 16 + (ln & 15), scol = kt * 32 + (ln >> 4) * 8 + j;
    W2s[e] = (bf16_t)W2[srow * 512 + scol];
  } else if (idx < S1 + S2 + S3) {                  // Bt[j][k] = W2[k][j]*w3[k], NT=32, KT=16
    const long e = idx - S1 - S2;
    const int j = (int)(e & 7), ln = (int)((e >> 3) & 63), tile = (int)(e >> 9);
    const int nt = tile & 31, kt = tile >> 5;
    const int srow = nt * 16 + (ln & 15), scol = kt * 32 + (ln >> 4) * 8 + j;
    W2ts[e] = (bf16_t)(W2[scol * 512 + srow] * W3[scol]);
  } else if (idx < S1 + S2 + S3 + S4) {             // Bt[j][k] = W1[k][j], j<128, NT=8, KT=16
    const long e = idx - S1 - S2 - S3;
    const int j = (int)(e & 7), ln = (int)((e >> 3) & 63), tile = (int)(e >> 9);
    const int nt = tile & 7, kt = tile >> 3;
    const int srow = nt * 16 + (ln & 15), scol = kt * 32 + (ln >> 4) * 8 + j;
    W1ts[e] = (bf16_t)W1[scol * 192 + srow];
  }
}

// ---------------- launch ----------------

extern "C" void kernel_launch(void* const* d_in, const int* in_sizes, int n_in,
                              void* d_out, int out_size, void* d_ws, size_t ws_size,
                              hipStream_t stream)
{
  const float* z_dyn    = (const float*)d_in[0];
  const float* z_static = (const float*)d_in[1];
  const float* dtp      = (const float*)d_in[2];
  const float* ut       = (const float*)d_in[3];
  const float* W1       = (const float*)d_in[4];
  const float* b1       = (const float*)d_in[5];
  const float* W2       = (const float*)d_in[6];
  const float* b2       = (const float*)d_in[7];
  const float* W3       = (const float*)d_in[8];
  const float* Bc       = (const float*)d_in[10];
  const float* Cm       = (const float*)d_in[11];
  const float* Dm       = (const float*)d_in[12];

  float* z_out  = (float*)d_out;            // B x 128
  float* yt_out = z_out + BATCH * 128;      // B x 20

  char* ws = (char*)d_ws;
  size_t off = 0;
  auto alloc = [&](size_t bytes) {
    char* p = ws + off;
    off = (off + bytes + 255) & ~(size_t)255;
    return p;
  };
  bf16_t* W1s  = (bf16_t*)alloc(98304 * 2);
  bf16_t* W2s  = (bf16_t*)alloc(262144 * 2);
  bf16_t* W2ts = (bf16_t*)alloc(262144 * 2);
  // +32KB slack retained (harmless; ping-pong tail reads stay in-bounds anyway).
  bf16_t* W1ts = (bf16_t*)alloc(65536 * 2 + 32768);
  (void)ws_size; (void)in_sizes; (void)n_in; (void)out_size;

  prep_shuffle<<<2688, 256, 0, stream>>>(W1, W2, W3, W1s, W2s, W2ts, W1ts);
  ham_fused<<<(int)(BATCH / ROWS), 512, 0, stream>>>(
      z_dyn, z_static, dtp, ut, b1, b2, W1s, W2s, W2ts, W1ts, Bc, Cm, Dm, z_out, yt_out);
}

// Round 12
// 444.868 us; speedup vs baseline: 1.1202x; 1.1202x over previous
//
#include <hip/hip_runtime.h>
#include <hip/hip_bf16.h>
#include <math.h>

typedef __bf16 bf16_t;
typedef __bf16 bf16x8 __attribute__((ext_vector_type(8)));
typedef __bf16 bf16x4 __attribute__((ext_vector_type(4)));
typedef float floatx4 __attribute__((ext_vector_type(4)));

#define BATCH 65536L
#define ROWS 64
#define MFMA __builtin_amdgcn_mfma_f32_16x16x32_bf16

// ---------------- helpers ----------------

__device__ __forceinline__ float softplus_f(float x) {
  const float l = __logf(1.f + __expf(x));
  return (x > 15.f) ? x : l;
}
__device__ __forceinline__ float sigmoid_f(float x) {
  return __builtin_amdgcn_rcpf(1.f + __expf(-x));
}

// fragment-linear activation store/load: element block (row=mf*16+lr, cols c0..c0+3)
__device__ __forceinline__ void store_frag(char* buf, int NKT, int mf, int c0, int lr, bf16x4 v) {
  const int kt = c0 >> 5, lkp = (c0 & 31) >> 3, j0 = c0 & 7;
  *(bf16x4*)(buf + (((mf * NKT + kt) * 64) + lr + 16 * lkp) * 16 + j0 * 2) = v;
}
__device__ __forceinline__ bf16x4 load_frag(const char* buf, int NKT, int mf, int c0, int lr) {
  const int kt = c0 >> 5, lkp = (c0 & 31) >> 3, j0 = c0 & 7;
  return *(const bf16x4*)(buf + (((mf * NKT + kt) * 64) + lr + 16 * lkp) * 16 + j0 * 2);
}

// ---------------- ring-pipelined frag-linear GEMM (session best, 444.96us) -------
// Weights kt-major: [kt][NT][lane][8]. A from LDS: [mf][KT][lane][8].
// R29 = byte-identical restore of R27/R22 after the full structural sweep:
//   reg-file wall (NF=4, 16-wave, unroll, barrier-hoist -> spill at >128 VGPR),
//   per-CU L2 weight stream is 1x-only (2-block split -23%),
//   A/W traffic balance of the 1x8 grid already matches LDS:L2 BW 2:1
//   (transposed 2x4 grid -12%), prefetch depth neutral (ring vs ping-pong),
//   K-desync negative. MF=4, NF=2, two N-passes, 88 VGPR, rolled 4-stage
//   weight ring (distance 3), A ping-pong (distance 1).
// MfmaUtil ~34% + VALUBusy ~50% = the measured plain-HIP 2-barrier ceiling.

template<int MF, int KT, int NT, int NF>
__device__ __forceinline__ void gemmP(const char* Abuf, const bf16_t* W, int ntb,
                                      int lane, floatx4 (&acc)[MF][NF])
{
  static_assert(KT % 4 == 0, "KT must be a multiple of the ring period");
  const char* wp = (const char*)W + (ntb * 64 + lane) * 16;
  const char* ap = Abuf + lane * 16;
  bf16x8 bv[4][NF];   // weight ring, 4 stages (prefetch distance 3)
  bf16x8 av[2][MF];   // A ping-pong (distance 1)
#pragma unroll
  for (int st = 0; st < 3; ++st)
#pragma unroll
    for (int nf = 0; nf < NF; ++nf)
      bv[st][nf] = *(const bf16x8*)(wp + (st * NT + nf) * 1024);
#pragma unroll
  for (int m = 0; m < MF; ++m)
    av[0][m] = *(const bf16x8*)(ap + m * KT * 1024);
#pragma unroll 1
  for (int b = 0; b < KT / 4; ++b) {
#pragma unroll
    for (int c = 0; c < 4; ++c) {
      // A for cluster c+1 (distance 1; last body's c=3 reads 1KB past A -- LDS-safe)
#pragma unroll
      for (int m = 0; m < MF; ++m)
        av[(c + 1) & 1][m] = *(const bf16x8*)(ap + ((c + 1) + m * KT) * 1024);
      // weights for cluster c+3 (distance 3; tail reads land in padded slack)
#pragma unroll
      for (int nf = 0; nf < NF; ++nf)
        bv[(c + 3) & 3][nf] = *(const bf16x8*)(wp + ((c + 3) * NT + nf) * 1024);
      __builtin_amdgcn_s_setprio(1);
#pragma unroll
      for (int m = 0; m < MF; ++m)
#pragma unroll
        for (int nf = 0; nf < NF; ++nf)
          acc[m][nf] = MFMA(bv[c & 3][nf], av[c & 1][m], acc[m][nf], 0, 0, 0);
      __builtin_amdgcn_s_setprio(0);
    }
    wp += 4 * NT * 1024;
    ap += 4 * 1024;
  }
}

// GEMM1: K=192 = zf_dyn (NKT=4) + zstat (NKT=2); weights NT=32, KT=6; kt pairs
// (0,1),(2,3) read zf; (4,5) read zst. MF=4, NF=2. Ping-pong (KT=6 doesn't fit
// the ring period; G1 is only 14% of MFMAs).
__device__ __forceinline__ void gemm_g1(const char* zf, const char* zs, const bf16_t* W,
                                        int ntb, int lane, floatx4 (&acc)[4][2])
{
  const char* wp = (const char*)W + (ntb * 64 + lane) * 16;
  bf16x8 bv0[2], bv1[2];
#pragma unroll
  for (int nf = 0; nf < 2; ++nf) bv0[nf] = *(const bf16x8*)(wp + nf * 1024);
#pragma unroll 1
  for (int kt = 0; kt < 6; kt += 2) {
    const char* ab = (kt < 4) ? (zf + kt * 1024 + lane * 16)
                              : (zs + (kt - 4) * 1024 + lane * 16);
    const int  ms = (kt < 4) ? 4096 : 2048;   // mf stride (NKT*1024)
#pragma unroll
    for (int nf = 0; nf < 2; ++nf)
      bv1[nf] = *(const bf16x8*)(wp + 32 * 1024 + nf * 1024);
    bf16x8 a[4];
#pragma unroll
    for (int m = 0; m < 4; ++m) a[m] = *(const bf16x8*)(ab + m * ms);
    __builtin_amdgcn_s_setprio(1);
#pragma unroll
    for (int m = 0; m < 4; ++m)
#pragma unroll
      for (int nf = 0; nf < 2; ++nf)
        acc[m][nf] = MFMA(bv0[nf], a[m], acc[m][nf], 0, 0, 0);
    __builtin_amdgcn_s_setprio(0);
    if (kt + 2 < 6) {
#pragma unroll
      for (int nf = 0; nf < 2; ++nf)
        bv0[nf] = *(const bf16x8*)(wp + 64 * 1024 + nf * 1024);
    }
#pragma unroll
    for (int m = 0; m < 4; ++m) a[m] = *(const bf16x8*)(ab + 1024 + m * ms);
    __builtin_amdgcn_s_setprio(1);
#pragma unroll
    for (int m = 0; m < 4; ++m)
#pragma unroll
      for (int nf = 0; nf < 2; ++nf)
        acc[m][nf] = MFMA(bv1[nf], a[m], acc[m][nf], 0, 0, 0);
    __builtin_amdgcn_s_setprio(0);
    wp += 64 * 1024;
  }
}

// ---------------- fused kernel: 64 rows/block, 8 waves (512 thr), 1 block/CU ------

__global__ __launch_bounds__(512, 1)
void ham_fused(const float* __restrict__ z_dyn, const float* __restrict__ z_static,
               const float* __restrict__ dtp, const float* __restrict__ ut,
               const float* __restrict__ b1, const float* __restrict__ b2,
               const bf16_t* __restrict__ W1s, const bf16_t* __restrict__ W2s,
               const bf16_t* __restrict__ W2ts, const bf16_t* __restrict__ W1ts,
               const float* __restrict__ Bc, const float* __restrict__ Cm,
               const float* __restrict__ Dm,
               float* __restrict__ z_out, float* __restrict__ yt_out)
{
  __shared__ __align__(16) char bufX[65536];   // h1 -> g1 (NKT=16, mf 0..3); later f32 z (stride 132)
  __shared__ __align__(16) char bufY[65536];   // zf (NKT=4) -> g2 (NKT=16); later Cm (stride 132)
  __shared__ __align__(16) char zst[8192];     // z_static frags (NKT=2, mf 0..3); later Dm
  __shared__ __align__(16) float uBs[64 * 68]; // uB, padded stride 68

  const int tid  = threadIdx.x;
  const int lane = tid & 63;
  const int w    = tid >> 6;      // 0..7
  const int lr   = lane & 15;
  const int lk   = lane >> 4;     // 0..3
  const long rb  = (long)blockIdx.x * ROWS;

  // dt is wave-uniform: pin to SGPR
  const float dtv = __builtin_bit_cast(float,
      __builtin_amdgcn_readfirstlane(__builtin_bit_cast(int, dtp[0])));
  const float hstep = dtv * 0.25f;
  const int   pcb   = ((w + 4) & 7) * 16;   // partner col base for z layout

  // ---- init: Bc -> bufX (f32), z_static -> zst (frag-linear bf16), zp regs
  for (int e = tid; e < 64 * 16; e += 512) ((float*)bufX)[e] = Bc[e];
  for (int e = tid; e < ROWS * 64; e += 512) {
    const int rr = e >> 6, cc = e & 63;
    const float v = __builtin_nontemporal_load(z_static + (rb + rr) * 64 + cc);
    const int kt = cc >> 5, lkp = (cc & 31) >> 3, j = cc & 7;
    *(bf16_t*)(zst + ((((rr >> 4) * 2 + kt) * 64) + (rr & 15) + 16 * lkp) * 16 + j * 2) = (bf16_t)v;
  }
  floatx4 zp[4];
#pragma unroll
  for (int m = 0; m < 4; ++m)
    zp[m] = __builtin_nontemporal_load(
        (const floatx4*)(z_dyn + (rb + m * 16 + lr) * 128 + pcb + lk * 4));
  __syncthreads();

  // ---- uB -> LDS (reads Bc from bufX; bufX reused after B1)
  for (int e = tid; e < ROWS * 64; e += 512) {
    const int rr = e >> 6, cc = e & 63;
    const float* ur = ut + (rb + rr) * 16;
    const float* bc = (const float*)bufX + cc * 16;
    float s = 0.f;
#pragma unroll
    for (int u = 0; u < 16; ++u) s += ur[u] * bc[u];
    uBs[rr * 68 + cc] = s;
  }

  for (int s = 0; s < 4; ++s) {
    // ---- pack zf (bufY, NKT=4) from z regs (all 4 row-frags, own partner cols)
#pragma unroll
    for (int m = 0; m < 4; ++m) {
      bf16x4 o;
#pragma unroll
      for (int i = 0; i < 4; ++i) o[i] = (bf16_t)zp[m][i];
      store_frag(bufY, 4, m, pcb + lk * 4, lr, o);
    }
    __syncthreads();   // B1: zf+uBs ready; everyone past GEMM4/bufX reads (or Bc reads)

    // ---- GEMM1 -> h1 (bufX), two 256-col passes
#pragma unroll 1
    for (int p = 0; p < 2; ++p) {
      floatx4 acc[4][2] = {};
      gemm_g1(bufY, zst, W1s, p * 16 + w * 2, lane, acc);
#pragma unroll
      for (int m = 0; m < 4; ++m)
#pragma unroll
        for (int nf = 0; nf < 2; ++nf) {
          const int c0 = p * 256 + w * 32 + nf * 16 + lk * 4;
          const floatx4 b4 = *(const floatx4*)(b1 + c0);
          bf16x4 h4;
#pragma unroll
          for (int i = 0; i < 4; ++i) h4[i] = (bf16_t)softplus_f(acc[m][nf][i] + b4[i]);
          store_frag(bufX, 16, m, c0, lr, h4);
        }
    }
    __syncthreads();   // B2: h1 ready

    // ---- GEMM2 -> g2 = sigmoid(a2+b2) (bufY), two passes  [w3 folded into W2ts]
#pragma unroll 1
    for (int p = 0; p < 2; ++p) {
      floatx4 acc[4][2] = {};
      gemmP<4, 16, 32, 2>(bufX, W2s, p * 16 + w * 2, lane, acc);
#pragma unroll
      for (int m = 0; m < 4; ++m)
#pragma unroll
        for (int nf = 0; nf < 2; ++nf) {
          const int c0 = p * 256 + w * 32 + nf * 16 + lk * 4;
          const floatx4 b4 = *(const floatx4*)(b2 + c0);
          bf16x4 g4;
#pragma unroll
          for (int i = 0; i < 4; ++i) g4[i] = (bf16_t)sigmoid_f(acc[m][nf][i] + b4[i]);
          store_frag(bufY, 16, m, c0, lr, g4);
        }
    }
    __syncthreads();   // B3: g2 ready

    // ---- GEMM3 -> g1 = s1 * (g2 @ (w3.W2)) (bufX), two passes
#pragma unroll 1
    for (int p = 0; p < 2; ++p) {
      floatx4 acc[4][2] = {};
      gemmP<4, 16, 32, 2>(bufY, W2ts, p * 16 + w * 2, lane, acc);
#pragma unroll
      for (int m = 0; m < 4; ++m)
#pragma unroll
        for (int nf = 0; nf < 2; ++nf) {
          const int c0 = p * 256 + w * 32 + nf * 16 + lk * 4;
          const bf16x4 h4 = load_frag(bufX, 16, m, c0, lr);   // lane-private bytes
          bf16x4 g4;
#pragma unroll
          for (int i = 0; i < 4; ++i) {
            const float s1 = 1.f - __expf(-(float)h4[i]);     // sigmoid(a1) from h1
            g4[i] = (bf16_t)(s1 * acc[m][nf][i]);
          }
          store_frag(bufX, 16, m, c0, lr, g4);
        }
    }
    __syncthreads();   // B4: g1 ready

    // ---- GEMM4: dH col block w*16; z update (partner layout, in regs)
    {
      floatx4 a4[4][1] = {};
      gemmP<4, 16, 8, 1>(bufX, W1ts, w, lane, a4);
#pragma unroll
      for (int m = 0; m < 4; ++m) {
        if (w < 4) {
          const float* ub = &uBs[(m * 16 + lr) * 68 + w * 16 + lk * 4];
#pragma unroll
          for (int i = 0; i < 4; ++i) zp[m][i] += hstep * (ub[i] - a4[m][0][i]);
        } else {
#pragma unroll
          for (int i = 0; i < 4; ++i) zp[m][i] += hstep * a4[m][0][i];
        }
      }
    }
    // next B1 separates GEMM4 bufX reads from GEMM1 bufX writes
  }

  // ---- final z store (nontemporal) + stage for yt (stride 132 floats)
#pragma unroll
  for (int m = 0; m < 4; ++m)
    __builtin_nontemporal_store(zp[m],
        (floatx4*)(z_out + (rb + m * 16 + lr) * 128 + pcb + lk * 4));
  __syncthreads();   // all GEMM4 bufX reads done
#pragma unroll
  for (int m = 0; m < 4; ++m)
    *(floatx4*)((float*)bufX + (m * 16 + lr) * 132 + pcb + lk * 4) = zp[m];
  for (int e = tid; e < 20 * 128; e += 512) {
    const int o = e >> 7, i = e & 127;
    ((float*)bufY)[o * 132 + i] = Cm[e];
  }
  for (int e = tid; e < 20 * 16; e += 512) ((float*)zst)[e] = Dm[e];
  __syncthreads();

  for (int q = tid; q < ROWS * 20; q += 512) {
    const int rr = q / 20, o = q - rr * 20;
    const float* zr = (const float*)bufX + rr * 132;
    const float* cr = (const float*)bufY + o * 132;
    float sm = 0.f;
#pragma unroll 4
    for (int i = 0; i < 128; ++i) sm += zr[i] * cr[i];
    float su = 0.f;
#pragma unroll
    for (int u = 0; u < 16; ++u)
      su += __builtin_nontemporal_load(ut + (rb + rr) * 16 + u) * ((const float*)zst)[o * 16 + u];
    __builtin_nontemporal_store(sm + dtv * su, yt_out + (rb + rr) * 20 + o);
  }
}

// ---------------- prep: kt-major fragment-linear shuffled weights ----------------
// shuf[((kt*NT + nt)*64 + ln)*8 + j] = Bt[nt*16 + (ln&15)][kt*32 + (ln>>4)*8 + j]

__global__ void prep_shuffle(const float* W1, const float* W2, const float* W3,
                             bf16_t* W1s, bf16_t* W2s, bf16_t* W2ts, bf16_t* W1ts)
{
  const long idx = (long)blockIdx.x * 256 + threadIdx.x;
  const long S1 = 98304, S2 = 262144, S3 = 262144, S4 = 65536;
  if (idx < S1) {                                   // Bt = W1 (512 x 192), NT=32, KT=6
    const long e = idx;
    const int j = (int)(e & 7), ln = (int)((e >> 3) & 63), tile = (int)(e >> 9);
    const int nt = tile & 31, kt = tile >> 5;
    const int srow = nt * 16 + (ln & 15), scol = kt * 32 + (ln >> 4) * 8 + j;
    W1s[e] = (bf16_t)W1[srow * 192 + scol];
  } else if (idx < S1 + S2) {                       // Bt = W2 (512 x 512), NT=32, KT=16
    const long e = idx - S1;
    const int j = (int)(e & 7), ln = (int)((e >> 3) & 63), tile = (int)(e >> 9);
    const int nt = tile & 31, kt = tile >> 5;
    const int srow = nt * 16 + (ln & 15), scol = kt * 32 + (ln >> 4) * 8 + j;
    W2s[e] = (bf16_t)W2[srow * 512 + scol];
  } else if (idx < S1 + S2 + S3) {                  // Bt[j][k] = W2[k][j]*w3[k], NT=32, KT=16
    const long e = idx - S1 - S2;
    const int j = (int)(e & 7), ln = (int)((e >> 3) & 63), tile = (int)(e >> 9);
    const int nt = tile & 31, kt = tile >> 5;
    const int srow = nt * 16 + (ln & 15), scol = kt * 32 + (ln >> 4) * 8 + j;
    W2ts[e] = (bf16_t)(W2[scol * 512 + srow] * W3[scol]);
  } else if (idx < S1 + S2 + S3 + S4) {             // Bt[j][k] = W1[k][j], j<128, NT=8, KT=16
    const long e = idx - S1 - S2 - S3;
    const int j = (int)(e & 7), ln = (int)((e >> 3) & 63), tile = (int)(e >> 9);
    const int nt = tile & 7, kt = tile >> 3;
    const int srow = nt * 16 + (ln & 15), scol = kt * 32 + (ln >> 4) * 8 + j;
    W1ts[e] = (bf16_t)W1[scol * 192 + srow];
  }
}

// ---------------- launch ----------------

extern "C" void kernel_launch(void* const* d_in, const int* in_sizes, int n_in,
                              void* d_out, int out_size, void* d_ws, size_t ws_size,
                              hipStream_t stream)
{
  const float* z_dyn    = (const float*)d_in[0];
  const float* z_static = (const float*)d_in[1];
  const float* dtp      = (const float*)d_in[2];
  const float* ut       = (const float*)d_in[3];
  const float* W1       = (const float*)d_in[4];
  const float* b1       = (const float*)d_in[5];
  const float* W2       = (const float*)d_in[6];
  const float* b2       = (const float*)d_in[7];
  const float* W3       = (const float*)d_in[8];
  const float* Bc       = (const float*)d_in[10];
  const float* Cm       = (const float*)d_in[11];
  const float* Dm       = (const float*)d_in[12];

  float* z_out  = (float*)d_out;            // B x 128
  float* yt_out = z_out + BATCH * 128;      // B x 20

  char* ws = (char*)d_ws;
  size_t off = 0;
  auto alloc = [&](size_t bytes) {
    char* p = ws + off;
    off = (off + bytes + 255) & ~(size_t)255;
    return p;
  };
  bf16_t* W1s  = (bf16_t*)alloc(98304 * 2);
  bf16_t* W2s  = (bf16_t*)alloc(262144 * 2);
  bf16_t* W2ts = (bf16_t*)alloc(262144 * 2);
  // +32KB slack: ring prefetch (distance 3) reads up to 3 clusters (3 x 8KB for
  // the G4 layout) past the logical end of W1ts; keep those reads in-bounds.
  bf16_t* W1ts = (bf16_t*)alloc(65536 * 2 + 32768);
  (void)ws_size; (void)in_sizes; (void)n_in; (void)out_size;

  prep_shuffle<<<2688, 256, 0, stream>>>(W1, W2, W3, W1s, W2s, W2ts, W1ts);
  ham_fused<<<(int)(BATCH / ROWS), 512, 0, stream>>>(
      z_dyn, z_static, dtp, ut, b1, b2, W1s, W2s, W2ts, W1ts, Bc, Cm, Dm, z_out, yt_out);
}